// Round 7
// baseline (5206.001 us; speedup 1.0000x reference)
//
#include <hip/hip_runtime.h>
#include <stdint.h>

typedef unsigned short u16;
typedef unsigned int   u32;
typedef __attribute__((ext_vector_type(8))) short short8;
typedef __attribute__((ext_vector_type(4))) float f32x4;

#define CAP   52

__device__ __forceinline__ u16 rne_bf16(float f){
  u32 u = __float_as_uint(f);
  u32 r = (u + 0x7fffu + ((u >> 16) & 1u)) >> 16;
  return (u16)r;
}
__device__ __forceinline__ float bf16_to_f(u16 h){
  return __uint_as_float(((u32)h) << 16);
}
__device__ __forceinline__ float tanh_fast(float x){
  float e = __expf(2.0f * x);
  return 1.0f - 2.0f / (e + 1.0f);
}

// ---------------------------------------------------------------------------
// A-pack: [xhi fbhi | xlo fblo], row m = b*1024+s, K=2048 bf16 bits
// ---------------------------------------------------------------------------
__global__ __launch_bounds__(256) void pack_a_k(const float* __restrict__ x,
                                                const float* __restrict__ fb,
                                                u16* __restrict__ A){
  int idx = blockIdx.x * 256 + threadIdx.x;          // 16384*512
  int m = idx >> 9, d = idx & 511;
  float xv = x[idx];
  float fv = fb[idx];
  u16 xh = rne_bf16(xv); u16 xl = rne_bf16(xv - bf16_to_f(xh));
  u16 fh = rne_bf16(fv); u16 fl = rne_bf16(fv - bf16_to_f(fh));
  size_t base = (size_t)m * 2048;
  A[base + d]        = xh;
  A[base + 512 + d]  = fh;
  A[base + 1024 + d] = xl;
  A[base + 1536 + d] = fl;
}

// ---------------------------------------------------------------------------
// B-pack with ROW PERMUTATION (col n of packed B = original row rowperm[n]).
// K=3072: [Winhi Wfbhi | Winhi Wfbhi | Winlo Wfblo]
// ---------------------------------------------------------------------------
__global__ __launch_bounds__(256) void pack_b_k(const float* __restrict__ Win,
                                                const float* __restrict__ Wfb,
                                                const int* __restrict__ rowperm,
                                                u16* __restrict__ Bm){
  int idx = blockIdx.x * 256 + threadIdx.x;          // 2048*512
  int n = idx >> 9, d = idx & 511;
  int row = rowperm[n];
  float iv = Win[(size_t)row * 512 + d];
  float fv = Wfb[(size_t)row * 512 + d];
  u16 ih = rne_bf16(iv); u16 il = rne_bf16(iv - bf16_to_f(ih));
  u16 fh = rne_bf16(fv); u16 fl = rne_bf16(fv - bf16_to_f(fh));
  size_t base = (size_t)n * 3072;
  Bm[base + d]        = ih;
  Bm[base + 512 + d]  = fh;
  Bm[base + 1024 + d] = ih;
  Bm[base + 1536 + d] = fh;
  Bm[base + 2048 + d] = il;
  Bm[base + 2560 + d] = fl;
}

// ---------------------------------------------------------------------------
// count nnz per row (one wave per row)
// ---------------------------------------------------------------------------
__global__ __launch_bounds__(256) void count_k(const float* __restrict__ W,
                                               int* __restrict__ nnz){
  int gt = blockIdx.x * 256 + threadIdx.x;
  int row = gt >> 6, l = gt & 63;
  const float* wr = W + (size_t)row * 2048;
  int c = 0;
  for (int i = 0; i < 32; i++) c += (wr[i * 64 + l] != 0.0f) ? 1 : 0;
  for (int off = 32; off; off >>= 1) c += __shfl_down(c, off, 64);
  if (l == 0) nnz[row] = c;
}

// ---------------------------------------------------------------------------
// Counting-sort rows desc by nnz, pair p <-> 2047-p; emit rowperm for pack_b.
// (Pairing is now purely for load balance: max pair-sum <= CAP.)
// ---------------------------------------------------------------------------
__global__ __launch_bounds__(1024) void sort_k(const int* __restrict__ nnz,
                                               u32* __restrict__ rowsp,
                                               int* __restrict__ rowperm){
  __shared__ int hist[64], off[64], cur[64];
  __shared__ int order[2048];
  int tid = threadIdx.x;
  if (tid < 64){ hist[tid] = 0; cur[tid] = 0; }
  __syncthreads();
  for (int r = tid; r < 2048; r += 1024){
    int b = nnz[r]; if (b > 63) b = 63;
    atomicAdd(&hist[b], 1);
  }
  __syncthreads();
  if (tid == 0){
    int run = 0;
    for (int b = 63; b >= 0; b--){ off[b] = run; run += hist[b]; }
  }
  __syncthreads();
  for (int r = tid; r < 2048; r += 1024){
    int b = nnz[r]; if (b > 63) b = 63;
    int pos = off[b] + atomicAdd(&cur[b], 1);
    order[pos] = r;
  }
  __syncthreads();
  int rA = order[tid], rB = order[2047 - tid];
  rowsp[tid] = (u32)rA | ((u32)rB << 16);
  rowperm[tid] = rA;
  rowperm[tid + 1024] = rB;
}

// ---------------------------------------------------------------------------
// Fill RAW item words (slot-major): [0,L1)=rowA then rowB (order is only a
// convention here; the scheduler may mix freely thanks to the sigma bit).
// raw = (bits(0.5*v) rounded at 10-bit mantissa, bits 31:13)
//     | (sigma = rowB flag) << 11 | column (11 bits).
// Weights are PRE-SCALED by 0.5: rnn computes aA = S1+S2, aB = S1-S2.
// ---------------------------------------------------------------------------
__global__ __launch_bounds__(256) void fill_k(const float* __restrict__ W,
                                              const u32* __restrict__ rowsp,
                                              u32* __restrict__ raw){
  int gt = blockIdx.x * 256 + threadIdx.x;
  int p = gt >> 6, l = gt & 63;
  u32 rp = rowsp[p];
  int rA = (int)(rp & 0xffffu), rB = (int)(rp >> 16);
  int base = 0;
  for (int h = 0; h < 2; h++){
    int row = h ? rB : rA;
    const float* wr = W + (size_t)row * 2048;
    int cnt = 0;
    for (int i = 0; i < 32; i++){
      int c = i * 64 + l;
      float v = wr[c];
      unsigned long long m = __ballot(v != 0.0f);
      int pre = __popcll(m & ((1ull << l) - 1ull));
      if (v != 0.0f){
        int s = base + cnt + pre;
        if (s < CAP){
          u32 u = __float_as_uint(0.5f * v);
          u = ((u + 0x1000u) & 0xFFFFE000u) | ((u32)h << 11) | (u32)c;
          raw[s * 1024 + p] = u;
        }
      }
      cnt += __popcll(m);
    }
    base += cnt;
  }
}

// ---------------------------------------------------------------------------
// FUSED GEMM + BANK SCHEDULER.
// Blocks 0..15: free-pool half-phase scheduler (barrier-free single wave).
//   Segment constraint is GONE (sigma bit carries row identity) -> per-slot
//   candidate pool doubles -> cap-1-per-(half,bank) matching has real slack.
// Blocks 16..2063: drive GEMM M=16384,N=2048,K=3072, 128x128 tile.
// Fusion hides the scheduler's ~300us under the GEMM.
// ---------------------------------------------------------------------------
#define GLDS(gp, lp) __builtin_amdgcn_global_load_lds( \
    (const __attribute__((address_space(1))) void*)(gp), \
    (__attribute__((address_space(3))) void*)(lp), 16, 0, 0)

__global__ __launch_bounds__(256) void gemmsched_k(const u16* __restrict__ A,
                                                   const u16* __restrict__ Bm,
                                                   float* __restrict__ C,
                                                   const u32* __restrict__ raw,
                                                   u32* __restrict__ wpk,
                                                   const u32* __restrict__ rowsp,
                                                   const int* __restrict__ nnz){
  __shared__ __align__(16) u16 As[128 * 32];
  __shared__ __align__(16) u16 Bs[128 * 32];
  __shared__ u32 pool[CAP * 64];
  __shared__ int cnt[64];                            // [half*32 + bank]

  if (blockIdx.x < 16){
    // ---------------- scheduler path (one wave) ----------------
    const int lane = threadIdx.x;
    if (lane >= 64) return;
    const int p = blockIdx.x * 64 + lane;
    const int hb = (lane >> 5) << 5;
    u32 rp = rowsp[p];
    int nT = nnz[rp & 0xffffu] + nnz[rp >> 16];
    if (nT > CAP) nT = CAP;
    for (int k = 0; k < CAP; k++) pool[k * 64 + lane] = raw[k * 1024 + p];
    unsigned long long used = 0ull;
    for (int s = 0; s < CAP; s++){
      cnt[lane] = 0;                                 // wave-ordered reset
      u32 word;
      if (s < nT){
        int chosen = -1;
        for (int capc = 1; chosen < 0; capc++){
          for (int j = 0; j < nT; j++){
            if (used & (1ull << j)) continue;
            int bk = (int)(pool[j * 64 + lane] & 31u);
            int old = atomicAdd(&cnt[hb + bk], 1);
            if (old < capc){ chosen = j; break; }
            atomicSub(&cnt[hb + bk], 1);
          }
        }
        used |= 1ull << chosen;
        u32 r = pool[chosen * 64 + lane];
        u32 vb = r & 0xFFFFE000u;
        u32 low = ((r & 0x7FFu) << 2) | ((r >> 11) & 1u);
        word = ((vb - low + 0x1000u) & 0xFFFFE000u) + low;
      } else {
        int bsel = -1;
        for (int capc = 1; bsel < 0; capc++){
          for (int bb = 0; bb < 32; bb++){
            int bk = (bb + lane) & 31;
            int old = atomicAdd(&cnt[hb + bk], 1);
            if (old < capc){ bsel = bk; break; }
            atomicSub(&cnt[hb + bk], 1);
          }
        }
        word = (u32)bsel << 2;                       // denormal value ~ 0
      }
      wpk[s * 1024 + p] = word;
    }
    return;
  }

  // ---------------- GEMM path ----------------
  const int tid = threadIdx.x;
  const int w = tid >> 6, l = tid & 63;
  const int bid = blockIdx.x - 16;
  const int mt = bid >> 4, nt = bid & 15;
  const int m0 = mt * 128, n0 = nt * 128;
  const int srow = tid >> 2;
  const int scol = (tid & 3) * 8;
  const int wr = w & 1, wc = w >> 1;
  const int lhi = l >> 4, llo = l & 15;

  f32x4 acc[4][4];
  #pragma unroll
  for (int i = 0; i < 4; i++)
    #pragma unroll
    for (int j = 0; j < 4; j++)
      acc[i][j] = (f32x4){0.f, 0.f, 0.f, 0.f};

  for (int kt = 0; kt < 96; ++kt){
    int k = kt * 32;
    int keff = (k >= 2048) ? (k - 2048) : k;
    #pragma unroll
    for (int r = 0; r < 2; r++){
      const u16* ga = A  + (size_t)(m0 + r * 64 + srow) * 2048 + keff + scol;
      GLDS(ga, &As[r * 2048 + w * 512]);
      const u16* gb = Bm + (size_t)(n0 + r * 64 + srow) * 3072 + k + scol;
      GLDS(gb, &Bs[r * 2048 + w * 512]);
    }
    __syncthreads();
    short8 af[4], bf[4];
    #pragma unroll
    for (int i = 0; i < 4; i++){
      af[i] = *(const short8*)&As[(wr * 64 + i * 16 + llo) * 32 + lhi * 8];
      bf[i] = *(const short8*)&Bs[(wc * 64 + i * 16 + llo) * 32 + lhi * 8];
    }
    #pragma unroll
    for (int i = 0; i < 4; i++)
      #pragma unroll
      for (int j = 0; j < 4; j++)
        acc[i][j] = __builtin_amdgcn_mfma_f32_16x16x32_bf16(af[i], bf[j], acc[i][j], 0, 0, 0);
    __syncthreads();
  }
  #pragma unroll
  for (int i = 0; i < 4; i++)
    #pragma unroll
    for (int j = 0; j < 4; j++)
      #pragma unroll
      for (int rg = 0; rg < 4; rg++){
        int mr = m0 + wr * 64 + i * 16 + lhi * 4 + rg;
        int nc = n0 + wc * 64 + j * 16 + llo;
        C[(size_t)mr * 2048 + nc] = acc[i][j][rg];
      }
}

// ---------------------------------------------------------------------------
// Recurrent kernel: 16 WGs (1 batch/CU), 1024 thr, 52 packed u32 in regs.
// NEW: sigma-bit inner loop (5 VALU/item: AND, LSHL, XOR, FMA, FMA;
//      aA = S1+S2, aB = S1-S2, weights pre-scaled 0.5) and state
//      DOUBLE-BUFFER (16KB) -> ONE barrier per step. Read/write buffer
//      selected by compile-time 0/8192 immediates in an unroll-x2 loop.
// ---------------------------------------------------------------------------
__global__ __attribute__((amdgpu_flat_work_group_size(1024, 1024),
                          amdgpu_waves_per_eu(4, 4)))
void rnn_k(float* __restrict__ out,
           const float* __restrict__ init,
           const u32* __restrict__ wpkg,
           const u32* __restrict__ rowsp){
  const int tid = threadIdx.x, b = blockIdx.x;
  u32 wk[CAP];
  #pragma unroll
  for (int k = 0; k < CAP; k++) wk[k] = wpkg[k * 1024 + tid];
  u32 rp = rowsp[tid];
  const int rA4 = (int)(rp & 0xffffu) << 2;
  const int rB4 = (int)(rp >> 16) << 2;

  __shared__ float st[4096];                         // [0]=buf0, [2048]=buf1
  st[tid]        = init[(size_t)b * 2048 + tid];
  st[tid + 1024] = init[(size_t)b * 2048 + tid + 1024];
  __syncthreads();
  const char* stb = (const char*)st;
  char* stw = (char*)st;
  const int t4a = tid << 2, t4b = (tid + 1024) << 2;

  float* ob = out + (size_t)b * 1024 * 2048;
  float dA = __builtin_nontemporal_load(&ob[tid]);
  float dB = __builtin_nontemporal_load(&ob[tid + 1024]);

#define ESN_STEP(T, RD, WR) { \
    float* orow = ob + (size_t)(T) * 2048; \
    const float* nrow = ob + (size_t)(((T) + 1) & 1023) * 2048; \
    float dA2 = __builtin_nontemporal_load(&nrow[tid]); \
    float dB2 = __builtin_nontemporal_load(&nrow[tid + 1024]); \
    float S1 = 0.f, S2 = 0.f; \
    _Pragma("unroll") \
    for (int k = 0; k < CAP; k++){ \
      u32 w = wk[k]; \
      float sv = *(const float*)(stb + (RD) + (w & 0x1FFCu)); \
      float wv  = __uint_as_float(w); \
      float wv2 = __uint_as_float(w ^ (w << 31)); \
      S1 = __builtin_fmaf(wv,  sv, S1); \
      S2 = __builtin_fmaf(wv2, sv, S2); \
    } \
    float sA = tanh_fast((S1 + S2) + dA); \
    float sB = tanh_fast((S1 - S2) + dB); \
    *(float*)(stw + (WR) + rA4) = sA; \
    *(float*)(stw + (WR) + rB4) = sB; \
    __syncthreads(); \
    __builtin_nontemporal_store(*(const float*)(stb + (WR) + t4a), &orow[tid]); \
    __builtin_nontemporal_store(*(const float*)(stb + (WR) + t4b), &orow[tid + 1024]); \
    dA = dA2; dB = dB2; \
  }

  for (int t = 0; t < 1024; t += 2){
    ESN_STEP(t, 0, 8192)
    ESN_STEP(t + 1, 8192, 0)
  }
#undef ESN_STEP
}

// ---------------------------------------------------------------------------
extern "C" void kernel_launch(void* const* d_in, const int* in_sizes, int n_in,
                              void* d_out, int out_size, void* d_ws, size_t ws_size,
                              hipStream_t stream) {
  const float* x    = (const float*)d_in[0];
  const float* fb   = (const float*)d_in[1];
  const float* init = (const float*)d_in[2];
  const float* Wres = (const float*)d_in[3];
  const float* Win  = (const float*)d_in[4];
  const float* Wfb  = (const float*)d_in[5];
  float* out = (float*)d_out;

  char* w8 = (char*)d_ws;
  u16*  A_pack = (u16*)(w8);                       // 67108864 B
  u16*  B_pack = (u16*)(w8 + 67108864);            // 12582912 B
  u32*  wpk    = (u32*) (w8 + 79691776);           // 52*1024*4 = 212992
  int*  nnz    = (int*) (w8 + 79904768);           // 8192
  u32*  rowsp  = (u32*) (w8 + 79912960);           // 4096
  int*  rowperm= (int*) (w8 + 79917056);           // 8192
  u32*  raw    = (u32*) (w8 + 79925248);           // 212992 -> end 80138240
                                                   // (raw must NOT alias out:
                                                   //  sched runs concurrent
                                                   //  with gemm's C writes)

  pack_a_k<<<32768, 256, 0, stream>>>(x, fb, A_pack);
  count_k<<<512, 256, 0, stream>>>(Wres, nnz);
  sort_k<<<1, 1024, 0, stream>>>(nnz, rowsp, rowperm);
  pack_b_k<<<4096, 256, 0, stream>>>(Win, Wfb, rowperm, B_pack);
  fill_k<<<256, 256, 0, stream>>>(Wres, rowsp, raw);
  gemmsched_k<<<2064, 256, 0, stream>>>(A_pack, B_pack, out, raw, wpk, rowsp, nnz);
  rnn_k<<<16, 1024, 0, stream>>>(out, init, wpk, rowsp);
}